// Round 1
// baseline (1441.333 us; speedup 1.0000x reference)
//
#include <hip/hip_runtime.h>
#include <math.h>

#define N_NODES 100000
#define N_EDGES 3200000
#define N_GRAPH 1000

// ---- float atomic-max via order-preserving uint mapping ----
__device__ __forceinline__ unsigned f2ord(float f) {
    unsigned u = __float_as_uint(f);
    return (u & 0x80000000u) ? ~u : (u | 0x80000000u);
}
__device__ __forceinline__ float ord2f(unsigned k) {
    return __uint_as_float((k & 0x80000000u) ? (k & 0x7fffffffu) : ~k);
}

// ---- node linear: x[N,IN] -> q,k,v,s [N,OUT] (W row-major [IN,OUT]) ----
template<int IN, int OUT>
__global__ void lin_qkvs_kernel(const float* __restrict__ x,
                                const float* __restrict__ Wq, const float* __restrict__ bq,
                                const float* __restrict__ Wk, const float* __restrict__ bk,
                                const float* __restrict__ Wv, const float* __restrict__ bv,
                                const float* __restrict__ Ws, const float* __restrict__ bs,
                                float* __restrict__ q, float* __restrict__ k,
                                float* __restrict__ v, float* __restrict__ s) {
    __shared__ float w[4][IN*OUT];
    __shared__ float bb[4][OUT];
    const float* Wsrc[4] = {Wq, Wk, Wv, Ws};
    const float* bsrc[4] = {bq, bk, bv, bs};
    for (int t = threadIdx.x; t < 4*IN*OUT; t += blockDim.x)
        w[t/(IN*OUT)][t%(IN*OUT)] = Wsrc[t/(IN*OUT)][t%(IN*OUT)];
    for (int t = threadIdx.x; t < 4*OUT; t += blockDim.x)
        bb[t/OUT][t%OUT] = bsrc[t/OUT][t%OUT];
    __syncthreads();
    int i = blockIdx.x*blockDim.x + threadIdx.x;
    if (i >= N_NODES) return;
    float xr[IN];
    #pragma unroll
    for (int r = 0; r < IN; ++r) xr[r] = x[(long)i*IN + r];
    float* outp[4] = {q, k, v, s};
    #pragma unroll
    for (int mtx = 0; mtx < 4; ++mtx) {
        #pragma unroll
        for (int c = 0; c < OUT; ++c) {
            float acc = bb[mtx][c];
            #pragma unroll
            for (int r = 0; r < IN; ++r) acc = fmaf(xr[r], w[mtx][r*OUT + c], acc);
            outp[mtx][(long)i*OUT + c] = acc;
        }
    }
}

// ---- init: m = ord(-1e30), denom = 0, agg = 0 ----
__global__ void init_kernel(unsigned* __restrict__ m, float* __restrict__ denom,
                            float* __restrict__ agg, int n, int nd) {
    int i = blockIdx.x*blockDim.x + threadIdx.x;
    if (i < n) { m[i] = f2ord(-1e30f); denom[i] = 0.0f; }
    if (i < nd) agg[i] = 0.0f;
}

// ---- edge pass 1: score[e] = scale * dot(q[dst], k[src]); atomicMax m[dst] ----
template<int D>
__global__ void score_kernel(const int* __restrict__ ei, const float* __restrict__ q,
                             const float* __restrict__ k, float* __restrict__ score,
                             unsigned* __restrict__ m, float scale) {
    int t = blockIdx.x*blockDim.x + threadIdx.x;
    int e = t / D;
    int j = t % D;
    if (e >= N_EDGES) return;
    int src = ei[e];
    int dst = ei[N_EDGES + e];
    float p = q[(long)dst*D + j] * k[(long)src*D + j];
    #pragma unroll
    for (int off = D/2; off >= 1; off >>= 1) p += __shfl_xor(p, off, 64);
    if (j == 0) {
        float sc = p * scale;
        score[e] = sc;
        atomicMax(&m[dst], f2ord(sc));
    }
}

// ---- edge pass 2 (fused): w = exp(score - m[dst]); denom[dst]+=w; agg[dst]+=w*v[src] ----
template<int D>
__global__ void aggexp_kernel(const int* __restrict__ ei, const float* __restrict__ v,
                              const float* __restrict__ score, const unsigned* __restrict__ m,
                              float* __restrict__ denom, float* __restrict__ agg) {
    int t = blockIdx.x*blockDim.x + threadIdx.x;
    int e = t / D;
    int j = t % D;
    if (e >= N_EDGES) return;
    int src = ei[e];
    int dst = ei[N_EDGES + e];
    float w = __expf(score[e] - ord2f(m[dst]));
    atomicAdd(&agg[(long)dst*D + j], w * v[(long)src*D + j]);
    if (j == 0) atomicAdd(&denom[dst], w);
}

// ---- node finalize: h = relu(agg/denom + skip) ----
template<int D>
__global__ void final_kernel(const float* __restrict__ agg, const float* __restrict__ denom,
                             const float* __restrict__ s, float* __restrict__ h) {
    int idx = blockIdx.x*blockDim.x + threadIdx.x;
    if (idx >= N_NODES*D) return;
    int i = idx / D;
    float d = denom[i];
    float a = (d > 0.0f) ? agg[idx] / d : 0.0f;
    float val = a + s[idx];
    h[idx] = val > 0.0f ? val : 0.0f;
}

__global__ void zero_kernel(float* __restrict__ p, int n) {
    int i = blockIdx.x*blockDim.x + threadIdx.x;
    if (i < n) p[i] = 0.0f;
}

// ---- pool: sums[b,c] += h2[i,c]; cnts[b] += 1 ----
__global__ void pool_kernel(const float* __restrict__ h2, const int* __restrict__ batch,
                            float* __restrict__ sums, float* __restrict__ cnts) {
    int idx = blockIdx.x*blockDim.x + threadIdx.x;
    if (idx >= N_NODES*32) return;
    int i = idx >> 5;
    int c = idx & 31;
    int b = batch[i];
    atomicAdd(&sums[b*32 + c], h2[idx]);
    if (c == 0) atomicAdd(&cnts[b], 1.0f);
}

// ---- head: pooled = sums/cnt; relu(pooled@Wf1+bf1)@Wf2+bf2 -> sigmoid ----
__global__ void head_kernel(const float* __restrict__ sums, const float* __restrict__ cnts,
                            const float* __restrict__ Wf1, const float* __restrict__ bf1,
                            const float* __restrict__ Wf2, const float* __restrict__ bf2,
                            float* __restrict__ out) {
    __shared__ float w1[32*64];
    __shared__ float b1[64];
    __shared__ float w2[64*2];
    __shared__ float b2[2];
    for (int t = threadIdx.x; t < 32*64; t += blockDim.x) w1[t] = Wf1[t];
    for (int t = threadIdx.x; t < 64; t += blockDim.x) b1[t] = bf1[t];
    for (int t = threadIdx.x; t < 128; t += blockDim.x) w2[t] = Wf2[t];
    if (threadIdx.x < 2) b2[threadIdx.x] = bf2[threadIdx.x];
    __syncthreads();
    int b = blockIdx.x*blockDim.x + threadIdx.x;
    if (b >= N_GRAPH) return;
    float inv = 1.0f / fmaxf(cnts[b], 1.0f);
    float pooled[32];
    #pragma unroll
    for (int c = 0; c < 32; ++c) pooled[c] = sums[b*32 + c] * inv;
    float z0 = b2[0], z1 = b2[1];
    for (int o = 0; o < 64; ++o) {
        float acc = b1[o];
        #pragma unroll
        for (int c = 0; c < 32; ++c) acc = fmaf(pooled[c], w1[c*64 + o], acc);
        acc = fmaxf(acc, 0.0f);
        z0 = fmaf(acc, w2[o*2 + 0], z0);
        z1 = fmaf(acc, w2[o*2 + 1], z1);
    }
    out[b*2 + 0] = 1.0f / (1.0f + __expf(-z0));
    out[b*2 + 1] = 1.0f / (1.0f + __expf(-z1));
}

extern "C" void kernel_launch(void* const* d_in, const int* in_sizes, int n_in,
                              void* d_out, int out_size, void* d_ws, size_t ws_size,
                              hipStream_t stream) {
    const float* x    = (const float*)d_in[0];
    const int*   ei   = (const int*)d_in[1];     // [2,E] -> src = ei[0:E], dst = ei[E:2E]
    const int*   batch= (const int*)d_in[2];
    const float* Wq1 = (const float*)d_in[3],  *bq1 = (const float*)d_in[4];
    const float* Wk1 = (const float*)d_in[5],  *bk1 = (const float*)d_in[6];
    const float* Wv1 = (const float*)d_in[7],  *bv1 = (const float*)d_in[8];
    const float* Ws1 = (const float*)d_in[9],  *bs1 = (const float*)d_in[10];
    const float* Wq2 = (const float*)d_in[11], *bq2 = (const float*)d_in[12];
    const float* Wk2 = (const float*)d_in[13], *bk2 = (const float*)d_in[14];
    const float* Wv2 = (const float*)d_in[15], *bv2 = (const float*)d_in[16];
    const float* Ws2 = (const float*)d_in[17], *bs2 = (const float*)d_in[18];
    const float* Wf1 = (const float*)d_in[19], *bf1 = (const float*)d_in[20];
    const float* Wf2 = (const float*)d_in[21], *bf2 = (const float*)d_in[22];
    float* out = (float*)d_out;

    // workspace layout (floats); ~97 MB total
    float* ws = (float*)d_ws;
    float* r1    = ws;                  // 6.4M: L1 {q1,k1,v1,s1} each 1.6M; L2 reuses as {q2,k2} each 3.2M
    float* h1    = r1 + 6400000;        // 1.6M
    float* v2    = h1 + 1600000;        // 3.2M
    float* s2    = v2 + 3200000;        // 3.2M
    float* h2    = s2 + 3200000;        // 3.2M
    float* agg   = h2 + 3200000;        // 3.2M (layer1 uses first 1.6M)
    float* score = agg + 3200000;       // 3.2M
    float* mbuf  = score + 3200000;     // 0.1M (as unsigned)
    float* denom = mbuf + 100000;       // 0.1M
    float* sums  = denom + 100000;      // 32000
    float* cnts  = sums + 32000;        // 1000  (contiguous with sums)

    float* q1 = r1;
    float* k1 = r1 + 1600000;
    float* v1 = r1 + 3200000;
    float* s1 = r1 + 4800000;
    float* q2 = r1;
    float* k2 = r1 + 3200000;
    unsigned* m_u = (unsigned*)mbuf;

    const int B = 256;
    const float scale1 = 0.25f;               // 1/sqrt(16)
    const float scale2 = 0.17677669529663687f; // 1/sqrt(32)

    // ---------- layer 1 (d=16) ----------
    lin_qkvs_kernel<9,16><<<(N_NODES + B-1)/B, B, 0, stream>>>(
        x, Wq1, bq1, Wk1, bk1, Wv1, bv1, Ws1, bs1, q1, k1, v1, s1);
    init_kernel<<<(N_NODES*16 + B-1)/B, B, 0, stream>>>(m_u, denom, agg, N_NODES, N_NODES*16);
    score_kernel<16><<<((long)N_EDGES*16 + B-1)/B, B, 0, stream>>>(ei, q1, k1, score, m_u, scale1);
    aggexp_kernel<16><<<((long)N_EDGES*16 + B-1)/B, B, 0, stream>>>(ei, v1, score, m_u, denom, agg);
    final_kernel<16><<<(N_NODES*16 + B-1)/B, B, 0, stream>>>(agg, denom, s1, h1);

    // ---------- layer 2 (d=32) ----------
    lin_qkvs_kernel<16,32><<<(N_NODES + B-1)/B, B, 0, stream>>>(
        h1, Wq2, bq2, Wk2, bk2, Wv2, bv2, Ws2, bs2, q2, k2, v2, s2);
    init_kernel<<<(N_NODES*32 + B-1)/B, B, 0, stream>>>(m_u, denom, agg, N_NODES, N_NODES*32);
    score_kernel<32><<<((long)N_EDGES*32 + B-1)/B, B, 0, stream>>>(ei, q2, k2, score, m_u, scale2);
    aggexp_kernel<32><<<((long)N_EDGES*32 + B-1)/B, B, 0, stream>>>(ei, v2, score, m_u, denom, agg);
    final_kernel<32><<<(N_NODES*32 + B-1)/B, B, 0, stream>>>(agg, denom, s2, h2);

    // ---------- pool + head ----------
    zero_kernel<<<(33000 + B-1)/B, B, 0, stream>>>(sums, 33000);
    pool_kernel<<<(N_NODES*32 + B-1)/B, B, 0, stream>>>(h2, batch, sums, cnts);
    head_kernel<<<(N_GRAPH + B-1)/B, B, 0, stream>>>(sums, cnts, Wf1, bf1, Wf2, bf2, out);
}

// Round 2
// 899.941 us; speedup vs baseline: 1.6016x; 1.6016x over previous
//
#include <hip/hip_runtime.h>
#include <math.h>

#define N_NODES 100000
#define N_EDGES 3200000
#define N_GRAPH 1000
#define NB_SCAN ((N_NODES + 255) / 256)   // 391 scan blocks

// =================== CSR build: hist + scan + scatter ===================

__global__ void zero_cnt_sums(int* __restrict__ cnt, float* __restrict__ sums) {
    int i = blockIdx.x*blockDim.x + threadIdx.x;
    if (i < N_NODES) cnt[i] = 0;
    if (i < N_GRAPH*32 + N_GRAPH) sums[i] = 0.0f;   // sums + cnts contiguous
}

__global__ void hist_kernel(const int* __restrict__ ei, int* __restrict__ cnt) {
    int e = blockIdx.x*blockDim.x + threadIdx.x;
    if (e < N_EDGES) atomicAdd(&cnt[ei[N_EDGES + e]], 1);
}

// per-block inclusive scan of cnt (256/block), emit partials + block sums
__global__ void scan1_kernel(const int* __restrict__ cnt, int* __restrict__ partial,
                             int* __restrict__ bsum) {
    __shared__ int sd[256];
    int t = threadIdx.x;
    int i = blockIdx.x*256 + t;
    int c = (i < N_NODES) ? cnt[i] : 0;
    sd[t] = c;
    __syncthreads();
    #pragma unroll
    for (int off = 1; off < 256; off <<= 1) {
        int v = (t >= off) ? sd[t-off] : 0;
        __syncthreads();
        sd[t] += v;
        __syncthreads();
    }
    if (i < N_NODES) partial[i] = sd[t];
    if (t == 255) bsum[blockIdx.x] = sd[t];
}

// single-block inclusive scan of the NB_SCAN block sums
__global__ void scan2_kernel(int* __restrict__ bsum) {
    __shared__ int sd[512];
    int t = threadIdx.x;
    sd[t] = (t < NB_SCAN) ? bsum[t] : 0;
    __syncthreads();
    #pragma unroll
    for (int off = 1; off < 512; off <<= 1) {
        int v = (t >= off) ? sd[t-off] : 0;
        __syncthreads();
        sd[t] += v;
        __syncthreads();
    }
    if (t < NB_SCAN) bsum[t] = sd[t];
}

// rowstart[i] = exclusive prefix; woff = copy for scatter cursor
__global__ void scan3_kernel(const int* __restrict__ partial, const int* __restrict__ cnt,
                             const int* __restrict__ bsum, int* __restrict__ rowstart,
                             int* __restrict__ woff) {
    int i = blockIdx.x*blockDim.x + threadIdx.x;
    if (i >= N_NODES) return;
    int b = i >> 8;
    int rs = partial[i] - cnt[i] + (b > 0 ? bsum[b-1] : 0);
    rowstart[i] = rs;
    woff[i] = rs;
}

// srcs[pos] = src, bucketed by dst
__global__ void scatter_kernel(const int* __restrict__ ei, int* __restrict__ woff,
                               int* __restrict__ srcs) {
    int e = blockIdx.x*blockDim.x + threadIdx.x;
    if (e >= N_EDGES) return;
    int src = ei[e];
    int dst = ei[N_EDGES + e];
    int p = atomicAdd(&woff[dst], 1);
    srcs[p] = src;
}

// =================== node linears: x -> q (scaled later), kv packed, skip ===================

template<int IN, int OUT>
__global__ void lin_qkvs_kernel(const float* __restrict__ x,
                                const float* __restrict__ Wq, const float* __restrict__ bq,
                                const float* __restrict__ Wk, const float* __restrict__ bk,
                                const float* __restrict__ Wv, const float* __restrict__ bv,
                                const float* __restrict__ Ws, const float* __restrict__ bs,
                                float* __restrict__ q, float* __restrict__ kv,
                                float* __restrict__ s) {
    __shared__ float w[4][IN*OUT];
    __shared__ float bb[4][OUT];
    const float* Wsrc[4] = {Wq, Wk, Wv, Ws};
    const float* bsrc[4] = {bq, bk, bv, bs};
    for (int t = threadIdx.x; t < 4*IN*OUT; t += blockDim.x)
        w[t/(IN*OUT)][t%(IN*OUT)] = Wsrc[t/(IN*OUT)][t%(IN*OUT)];
    for (int t = threadIdx.x; t < 4*OUT; t += blockDim.x)
        bb[t/OUT][t%OUT] = bsrc[t/OUT][t%OUT];
    __syncthreads();
    int i = blockIdx.x*blockDim.x + threadIdx.x;
    if (i >= N_NODES) return;
    float xr[IN];
    #pragma unroll
    for (int r = 0; r < IN; ++r) xr[r] = x[(long)i*IN + r];
    #pragma unroll
    for (int mtx = 0; mtx < 4; ++mtx) {
        #pragma unroll
        for (int c = 0; c < OUT; ++c) {
            float acc = bb[mtx][c];
            #pragma unroll
            for (int r = 0; r < IN; ++r) acc = fmaf(xr[r], w[mtx][r*OUT + c], acc);
            if (mtx == 0)      q[(long)i*OUT + c] = acc;
            else if (mtx == 1) kv[(long)i*2*OUT + c] = acc;          // k half
            else if (mtx == 2) kv[(long)i*2*OUT + OUT + c] = acc;    // v half
            else               s[(long)i*OUT + c] = acc;
        }
    }
}

// =================== fused attention gather (online softmax, no atomics) ===================

template<int D>
__global__ void attn_gather_kernel(const int* __restrict__ srcs,
                                   const int* __restrict__ rowstart,
                                   const int* __restrict__ cnt,
                                   const float* __restrict__ q,
                                   const float* __restrict__ kv,
                                   const float* __restrict__ s,
                                   float* __restrict__ h,
                                   float scale) {
    int tid = blockIdx.x*blockDim.x + threadIdx.x;
    int n = tid / D;         // destination node
    int j = tid % D;         // feature lane
    if (n >= N_NODES) return;
    float qreg = q[(long)n*D + j] * scale;
    int rs = rowstart[n];
    int deg = cnt[n];
    float m = -1e30f, l = 0.0f, acc = 0.0f;
    for (int p = rs; p < rs + deg; ++p) {
        int sn = srcs[p];
        const float* kvp = kv + (long)sn*2*D;
        float sc = qreg * kvp[j];
        #pragma unroll
        for (int off = D/2; off >= 1; off >>= 1) sc += __shfl_xor(sc, off, 64);
        float mn = fmaxf(m, sc);
        float r = __expf(m - mn);
        float f = __expf(sc - mn);
        l = l*r + f;
        acc = acc*r + f * kvp[D + j];
        m = mn;
    }
    float a = (deg > 0) ? acc / l : 0.0f;
    float val = a + s[(long)n*D + j];
    h[(long)n*D + j] = fmaxf(val, 0.0f);
}

// =================== pool + head ===================

__global__ void pool_kernel(const float* __restrict__ h2, const int* __restrict__ batch,
                            float* __restrict__ sums, float* __restrict__ cnts) {
    int idx = blockIdx.x*blockDim.x + threadIdx.x;
    if (idx >= N_NODES*32) return;
    int i = idx >> 5;
    int c = idx & 31;
    int b = batch[i];
    atomicAdd(&sums[b*32 + c], h2[idx]);
    if (c == 0) atomicAdd(&cnts[b], 1.0f);
}

__global__ void head_kernel(const float* __restrict__ sums, const float* __restrict__ cnts,
                            const float* __restrict__ Wf1, const float* __restrict__ bf1,
                            const float* __restrict__ Wf2, const float* __restrict__ bf2,
                            float* __restrict__ out) {
    __shared__ float w1[32*64];
    __shared__ float b1[64];
    __shared__ float w2[64*2];
    __shared__ float b2[2];
    for (int t = threadIdx.x; t < 32*64; t += blockDim.x) w1[t] = Wf1[t];
    for (int t = threadIdx.x; t < 64; t += blockDim.x) b1[t] = bf1[t];
    for (int t = threadIdx.x; t < 128; t += blockDim.x) w2[t] = Wf2[t];
    if (threadIdx.x < 2) b2[threadIdx.x] = bf2[threadIdx.x];
    __syncthreads();
    int b = blockIdx.x*blockDim.x + threadIdx.x;
    if (b >= N_GRAPH) return;
    float inv = 1.0f / fmaxf(cnts[b], 1.0f);
    float pooled[32];
    #pragma unroll
    for (int c = 0; c < 32; ++c) pooled[c] = sums[b*32 + c] * inv;
    float z0 = b2[0], z1 = b2[1];
    for (int o = 0; o < 64; ++o) {
        float acc = b1[o];
        #pragma unroll
        for (int c = 0; c < 32; ++c) acc = fmaf(pooled[c], w1[c*64 + o], acc);
        acc = fmaxf(acc, 0.0f);
        z0 = fmaf(acc, w2[o*2 + 0], z0);
        z1 = fmaf(acc, w2[o*2 + 1], z1);
    }
    out[b*2 + 0] = 1.0f / (1.0f + __expf(-z0));
    out[b*2 + 1] = 1.0f / (1.0f + __expf(-z1));
}

extern "C" void kernel_launch(void* const* d_in, const int* in_sizes, int n_in,
                              void* d_out, int out_size, void* d_ws, size_t ws_size,
                              hipStream_t stream) {
    const float* x    = (const float*)d_in[0];
    const int*   ei   = (const int*)d_in[1];     // [2,E]: src = ei[0:E], dst = ei[E:2E]
    const int*   batch= (const int*)d_in[2];
    const float* Wq1 = (const float*)d_in[3],  *bq1 = (const float*)d_in[4];
    const float* Wk1 = (const float*)d_in[5],  *bk1 = (const float*)d_in[6];
    const float* Wv1 = (const float*)d_in[7],  *bv1 = (const float*)d_in[8];
    const float* Ws1 = (const float*)d_in[9],  *bs1 = (const float*)d_in[10];
    const float* Wq2 = (const float*)d_in[11], *bq2 = (const float*)d_in[12];
    const float* Wk2 = (const float*)d_in[13], *bk2 = (const float*)d_in[14];
    const float* Wv2 = (const float*)d_in[15], *bv2 = (const float*)d_in[16];
    const float* Ws2 = (const float*)d_in[17], *bs2 = (const float*)d_in[18];
    const float* Wf1 = (const float*)d_in[19], *bf1 = (const float*)d_in[20];
    const float* Wf2 = (const float*)d_in[21], *bf2 = (const float*)d_in[22];
    float* out = (float*)d_out;

    // ---- workspace layout (4-byte units), ~84 MB ----
    char* wsb = (char*)d_ws;
    int*   srcs     = (int*)wsb;                         // 3.2M
    int*   cnt      = srcs + N_EDGES;                    // 100k
    int*   rowstart = cnt + N_NODES;                     // 100k
    int*   woff     = rowstart + N_NODES;                // 100k
    int*   bsum     = woff + N_NODES;                    // 512
    float* q        = (float*)(bsum + 512);              // 3.2M (layer2 size)
    float* kv       = q + 3200000;                       // 6.4M
    float* sB       = kv + 6400000;                      // 3.2M
    float* h1       = sB + 3200000;                      // 1.6M
    float* h2       = h1 + 1600000;                      // 3.2M
    float* sums     = h2 + 3200000;                      // 32000
    // cnts = sums + 32000 (contiguous, zeroed together)
    float* cnts     = sums + N_GRAPH*32;

    const int B = 256;
    const float scale1 = 0.25f;                // 1/sqrt(16)
    const float scale2 = 0.17677669529663687f; // 1/sqrt(32)

    // ---- CSR build (shared by both layers) + pool-buffer zero ----
    zero_cnt_sums<<<(N_NODES + B-1)/B, B, 0, stream>>>(cnt, sums);
    hist_kernel<<<(N_EDGES + B-1)/B, B, 0, stream>>>(ei, cnt);
    scan1_kernel<<<NB_SCAN, 256, 0, stream>>>(cnt, woff /*partial scratch*/, bsum);
    scan2_kernel<<<1, 512, 0, stream>>>(bsum);
    scan3_kernel<<<(N_NODES + B-1)/B, B, 0, stream>>>(woff, cnt, bsum, rowstart, woff);
    scatter_kernel<<<(N_EDGES + B-1)/B, B, 0, stream>>>(ei, woff, srcs);

    // ---- layer 1 (d=16) ----
    lin_qkvs_kernel<9,16><<<(N_NODES + B-1)/B, B, 0, stream>>>(
        x, Wq1, bq1, Wk1, bk1, Wv1, bv1, Ws1, bs1, q, kv, sB);
    attn_gather_kernel<16><<<((long)N_NODES*16 + B-1)/B, B, 0, stream>>>(
        srcs, rowstart, cnt, q, kv, sB, h1, scale1);

    // ---- layer 2 (d=32) ----
    lin_qkvs_kernel<16,32><<<(N_NODES + B-1)/B, B, 0, stream>>>(
        h1, Wq2, bq2, Wk2, bk2, Wv2, bv2, Ws2, bs2, q, kv, sB);
    attn_gather_kernel<32><<<((long)N_NODES*32 + B-1)/B, B, 0, stream>>>(
        srcs, rowstart, cnt, q, kv, sB, h2, scale2);

    // ---- pool + head ----
    pool_kernel<<<(N_NODES*32 + B-1)/B, B, 0, stream>>>(h2, batch, sums, cnts);
    head_kernel<<<(N_GRAPH + B-1)/B, B, 0, stream>>>(sums, cnts, Wf1, bf1, Wf2, bf2, out);
}

// Round 3
// 655.637 us; speedup vs baseline: 2.1984x; 1.3726x over previous
//
#include <hip/hip_runtime.h>
#include <math.h>

#define N_NODES 100000
#define N_EDGES 3200000
#define N_GRAPH 1000
#define NSUB 4   // linked sublists per destination node

// =================== init: head = -1, pool sums/cnts = 0 ===================
__global__ void init_kernel(int* __restrict__ head, float* __restrict__ sums) {
    int i = blockIdx.x*blockDim.x + threadIdx.x;
    if (i < N_NODES*NSUB) head[i] = -1;
    if (i < N_GRAPH*33) sums[i] = 0.0f;   // sums[32000] + cnts[1000] contiguous
}

// =================== linked-list build: coalesced payload, atomicExch heads ===================
__global__ void build_ll(const int* __restrict__ ei, int* __restrict__ head,
                         int2* __restrict__ nsrc) {
    int e = blockIdx.x*blockDim.x + threadIdx.x;
    if (e >= N_EDGES) return;
    int src = ei[e];
    int dst = ei[N_EDGES + e];
    int old = atomicExch(&head[dst*NSUB + (e & (NSUB-1))], e);
    nsrc[e] = make_int2(old, src);   // coalesced 8B store at index e
}

// =================== node linears: x -> q, kv (float2 interleaved), skip ===================
template<int IN, int OUT>
__global__ void lin_qkvs_kernel(const float* __restrict__ x,
                                const float* __restrict__ Wq, const float* __restrict__ bq,
                                const float* __restrict__ Wk, const float* __restrict__ bk,
                                const float* __restrict__ Wv, const float* __restrict__ bv,
                                const float* __restrict__ Ws, const float* __restrict__ bs,
                                float* __restrict__ q, float2* __restrict__ kv2,
                                float* __restrict__ s) {
    __shared__ float w[4][IN*OUT];
    __shared__ float bb[4][OUT];
    const float* Wsrc[4] = {Wq, Wk, Wv, Ws};
    const float* bsrc[4] = {bq, bk, bv, bs};
    for (int t = threadIdx.x; t < 4*IN*OUT; t += blockDim.x)
        w[t/(IN*OUT)][t%(IN*OUT)] = Wsrc[t/(IN*OUT)][t%(IN*OUT)];
    for (int t = threadIdx.x; t < 4*OUT; t += blockDim.x)
        bb[t/OUT][t%OUT] = bsrc[t/OUT][t%OUT];
    __syncthreads();
    int i = blockIdx.x*blockDim.x + threadIdx.x;
    if (i >= N_NODES) return;
    float xr[IN];
    #pragma unroll
    for (int r = 0; r < IN; ++r) xr[r] = x[(long)i*IN + r];
    #pragma unroll
    for (int c = 0; c < OUT; ++c) {
        float aq = bb[0][c], ak = bb[1][c], av = bb[2][c], as = bb[3][c];
        #pragma unroll
        for (int r = 0; r < IN; ++r) {
            float xv = xr[r];
            aq = fmaf(xv, w[0][r*OUT + c], aq);
            ak = fmaf(xv, w[1][r*OUT + c], ak);
            av = fmaf(xv, w[2][r*OUT + c], av);
            as = fmaf(xv, w[3][r*OUT + c], as);
        }
        q[(long)i*OUT + c] = aq;
        kv2[(long)i*OUT + c] = make_float2(ak, av);
        s[(long)i*OUT + c] = as;
    }
}

// =================== fused attention gather: one wave per dst, LL walk ===================
// D=16: 4 groups x 1 list each; D=32: 2 groups x 2 lists each. Partial
// online-softmax states merged across groups via shuffles.
template<int D>
__global__ void attn_gather_ll(const int* __restrict__ head,
                               const int2* __restrict__ nsrc,
                               const float* __restrict__ q,
                               const float2* __restrict__ kv2,
                               const float* __restrict__ s,
                               float* __restrict__ h,
                               float scale) {
    constexpr int G = 64 / D;      // groups per wave
    constexpr int LPG = NSUB / G;  // sublists per group
    int n = blockIdx.x*(blockDim.x >> 6) + (threadIdx.x >> 6);  // wave id = dst node
    if (n >= N_NODES) return;
    int lane = threadIdx.x & 63;
    int grp = lane / D;
    int j = lane % D;
    float qreg = q[(long)n*D + j] * scale;
    float m = -1e30f, l = 0.0f, acc = 0.0f;
    #pragma unroll
    for (int li = 0; li < LPG; ++li) {
        int e = head[n*NSUB + grp*LPG + li];
        while (e != -1) {
            int2 t = nsrc[e];                      // {next, src}
            float2 kvv = kv2[(long)t.y*D + j];     // {k_j, v_j}
            float sc = qreg * kvv.x;
            #pragma unroll
            for (int off = D/2; off >= 1; off >>= 1) sc += __shfl_xor(sc, off, 64);
            float mn = fmaxf(m, sc);
            float r = __expf(m - mn);
            float f = __expf(sc - mn);
            l = fmaf(l, r, f);
            acc = fmaf(acc, r, f * kvv.y);
            m = mn;
            e = t.x;
        }
    }
    // merge partial states across groups
    #pragma unroll
    for (int w = D; w < 64; w <<= 1) {
        float mo = __shfl_xor(m, w, 64);
        float lo = __shfl_xor(l, w, 64);
        float ao = __shfl_xor(acc, w, 64);
        float M = fmaxf(m, mo);
        float r = __expf(m - M), ro = __expf(mo - M);
        l = fmaf(l, r, lo * ro);
        acc = fmaf(acc, r, ao * ro);
        m = M;
    }
    if (grp == 0) {
        float a = (l > 0.0f) ? acc / l : 0.0f;
        float val = a + s[(long)n*D + j];
        h[(long)n*D + j] = fmaxf(val, 0.0f);
    }
}

// =================== pool: batch is sorted -> block-level LDS reduction ===================
__global__ void pool_kernel(const float* __restrict__ h2, const int* __restrict__ batch,
                            float* __restrict__ sums, float* __restrict__ cnts) {
    __shared__ float sd[256];
    int n0 = blockIdx.x * 8;                 // 8 nodes per block (100000/8 = 12500 exact)
    int t = threadIdx.x;
    int n = n0 + (t >> 5);
    int c = t & 31;
    int b = batch[n];
    float v = h2[(long)n*32 + c];
    int bfirst = batch[n0];
    int blast = batch[n0 + 7];
    if (bfirst == blast) {                   // block-uniform branch (usual case)
        sd[t] = v;
        __syncthreads();
        if (t < 128) sd[t] += sd[t + 128];
        __syncthreads();
        if (t < 64) sd[t] += sd[t + 64];
        __syncthreads();
        if (t < 32) atomicAdd(&sums[bfirst*32 + t], sd[t] + sd[t + 32]);
        if (t == 0) atomicAdd(&cnts[bfirst], 8.0f);
    } else {                                  // graph boundary in block (rare)
        atomicAdd(&sums[b*32 + c], v);
        if (c == 0) atomicAdd(&cnts[b], 1.0f);
    }
}

// =================== head MLP ===================
__global__ void head_kernel(const float* __restrict__ sums, const float* __restrict__ cnts,
                            const float* __restrict__ Wf1, const float* __restrict__ bf1,
                            const float* __restrict__ Wf2, const float* __restrict__ bf2,
                            float* __restrict__ out) {
    __shared__ float w1[32*64];
    __shared__ float b1[64];
    __shared__ float w2[64*2];
    __shared__ float b2[2];
    for (int t = threadIdx.x; t < 32*64; t += blockDim.x) w1[t] = Wf1[t];
    for (int t = threadIdx.x; t < 64; t += blockDim.x) b1[t] = bf1[t];
    for (int t = threadIdx.x; t < 128; t += blockDim.x) w2[t] = Wf2[t];
    if (threadIdx.x < 2) b2[threadIdx.x] = bf2[threadIdx.x];
    __syncthreads();
    int b = blockIdx.x*blockDim.x + threadIdx.x;
    if (b >= N_GRAPH) return;
    float inv = 1.0f / fmaxf(cnts[b], 1.0f);
    float pooled[32];
    #pragma unroll
    for (int c = 0; c < 32; ++c) pooled[c] = sums[b*32 + c] * inv;
    float z0 = b2[0], z1 = b2[1];
    for (int o = 0; o < 64; ++o) {
        float acc = b1[o];
        #pragma unroll
        for (int c = 0; c < 32; ++c) acc = fmaf(pooled[c], w1[c*64 + o], acc);
        acc = fmaxf(acc, 0.0f);
        z0 = fmaf(acc, w2[o*2 + 0], z0);
        z1 = fmaf(acc, w2[o*2 + 1], z1);
    }
    out[b*2 + 0] = 1.0f / (1.0f + __expf(-z0));
    out[b*2 + 1] = 1.0f / (1.0f + __expf(-z1));
}

extern "C" void kernel_launch(void* const* d_in, const int* in_sizes, int n_in,
                              void* d_out, int out_size, void* d_ws, size_t ws_size,
                              hipStream_t stream) {
    const float* x    = (const float*)d_in[0];
    const int*   ei   = (const int*)d_in[1];     // [2,E]: src = ei[0:E], dst = ei[E:2E]
    const int*   batch= (const int*)d_in[2];
    const float* Wq1 = (const float*)d_in[3],  *bq1 = (const float*)d_in[4];
    const float* Wk1 = (const float*)d_in[5],  *bk1 = (const float*)d_in[6];
    const float* Wv1 = (const float*)d_in[7],  *bv1 = (const float*)d_in[8];
    const float* Ws1 = (const float*)d_in[9],  *bs1 = (const float*)d_in[10];
    const float* Wq2 = (const float*)d_in[11], *bq2 = (const float*)d_in[12];
    const float* Wk2 = (const float*)d_in[13], *bk2 = (const float*)d_in[14];
    const float* Wv2 = (const float*)d_in[15], *bv2 = (const float*)d_in[16];
    const float* Ws2 = (const float*)d_in[17], *bs2 = (const float*)d_in[18];
    const float* Wf1 = (const float*)d_in[19], *bf1 = (const float*)d_in[20];
    const float* Wf2 = (const float*)d_in[21], *bf2 = (const float*)d_in[22];
    float* out = (float*)d_out;

    // ---- workspace layout, ~91.3 MB total ----
    // layer-1 q/kv/s live inside the layer-2-sized regions (gather1 completes
    // before lin2 overwrites them); h2 overlaps h1 (h1 dead after lin2).
    char* wsb = (char*)d_ws;
    int2*  nsrc = (int2*)wsb;                                 // 25.6 MB
    int*   head = (int*)(nsrc + N_EDGES);                     // 1.6 MB
    float* q    = (float*)(head + N_NODES*NSUB);              // 12.8 MB (D=32 size)
    float2* kv2 = (float2*)(q + N_NODES*32);                  // 25.6 MB
    float* sB   = (float*)(kv2 + N_NODES*32);                 // 12.8 MB
    float* h1   = sB + N_NODES*32;                            // region H: 12.8 MB
    float* h2   = h1;                                         //   h2 reuses H
    float* sums = h2 + N_NODES*32;                            // 128 KB
    float* cnts = sums + N_GRAPH*32;                          //   (contiguous)

    const int B = 256;
    const float scale1 = 0.25f;                // 1/sqrt(16)
    const float scale2 = 0.17677669529663687f; // 1/sqrt(32)

    init_kernel<<<(N_NODES*NSUB + B-1)/B, B, 0, stream>>>(head, sums);
    build_ll<<<(N_EDGES + B-1)/B, B, 0, stream>>>(ei, head, nsrc);

    // ---- layer 1 (d=16) ----
    lin_qkvs_kernel<9,16><<<(N_NODES + B-1)/B, B, 0, stream>>>(
        x, Wq1, bq1, Wk1, bk1, Wv1, bv1, Ws1, bs1, q, kv2, sB);
    attn_gather_ll<16><<<(N_NODES + 3)/4, B, 0, stream>>>(
        head, nsrc, q, kv2, sB, h1, scale1);

    // ---- layer 2 (d=32) ----
    lin_qkvs_kernel<16,32><<<(N_NODES + B-1)/B, B, 0, stream>>>(
        h1, Wq2, bq2, Wk2, bk2, Wv2, bv2, Ws2, bs2, q, kv2, sB);
    attn_gather_ll<32><<<(N_NODES + 3)/4, B, 0, stream>>>(
        head, nsrc, q, kv2, sB, h2, scale2);

    // ---- pool + head ----
    pool_kernel<<<N_NODES/8, B, 0, stream>>>(h2, batch, sums, cnts);
    head_kernel<<<(N_GRAPH + B-1)/B, B, 0, stream>>>(sums, cnts, Wf1, bf1, Wf2, bf2, out);
}